// Round 1
// baseline (873.080 us; speedup 1.0000x reference)
//
#include <hip/hip_runtime.h>
#include <math.h>

#define S_LEN 2048
#define B_SZ  64
#define H_SZ  1024
// DIN == 1024, rnn_input K = 2048

// ---------------- scores[b,s] = dot(h[b,:], enc[s,b,:]) ----------------
// one wave per (b,s); 16 floats/lane via 4 coalesced float4 loads
__global__ void k_scores(const float* __restrict__ h, const float* __restrict__ enc,
                         float* __restrict__ scores) {
    int w    = blockIdx.x * 4 + (threadIdx.x >> 6);   // global wave id, [0, 131072)
    int lane = threadIdx.x & 63;
    int b = w >> 11;          // [0,64)   b-major: consecutive waves share h row (L1)
    int s = w & 2047;         // [0,2048)
    const float* erow = enc + ((size_t)s * B_SZ + b) * H_SZ;
    const float* hrow = h + (size_t)b * H_SZ;
    float acc = 0.f;
#pragma unroll
    for (int i = 0; i < 4; ++i) {
        float4 e  = *(const float4*)(erow + i * 256 + lane * 4);
        float4 hh = *(const float4*)(hrow + i * 256 + lane * 4);
        acc += e.x * hh.x + e.y * hh.y + e.z * hh.z + e.w * hh.w;
    }
#pragma unroll
    for (int off = 32; off > 0; off >>= 1) acc += __shfl_xor(acc, off);
    if (lane == 0) scores[(size_t)b * S_LEN + s] = acc;
}

// ---------------- softmax over S per b; writes attn to d_out region ----------------
__global__ void k_softmax(const float* __restrict__ scores, float* __restrict__ attn) {
    int b = blockIdx.x, tid = threadIdx.x;
    __shared__ float sm[8];
    float v[8];
    float m = -1e30f;
#pragma unroll
    for (int i = 0; i < 8; ++i) {
        v[i] = scores[(size_t)b * S_LEN + tid + i * 256];
        m = fmaxf(m, v[i]);
    }
#pragma unroll
    for (int off = 32; off > 0; off >>= 1) m = fmaxf(m, __shfl_xor(m, off));
    if ((tid & 63) == 0) sm[tid >> 6] = m;
    __syncthreads();
    m = fmaxf(fmaxf(sm[0], sm[1]), fmaxf(sm[2], sm[3]));
    float l = 0.f;
#pragma unroll
    for (int i = 0; i < 8; ++i) { v[i] = expf(v[i] - m); l += v[i]; }
#pragma unroll
    for (int off = 32; off > 0; off >>= 1) l += __shfl_xor(l, off);
    __syncthreads();
    if ((tid & 63) == 0) sm[4 + (tid >> 6)] = l;
    __syncthreads();
    l = sm[4] + sm[5] + sm[6] + sm[7];
    float inv = 1.f / l;
#pragma unroll
    for (int i = 0; i < 8; ++i)
        attn[(size_t)b * S_LEN + tid + i * 256] = v[i] * inv;
}

// ---------------- zero ctx ----------------
__global__ void k_zero(float* __restrict__ p) {
    int idx = (blockIdx.x * 256 + threadIdx.x) * 4;
    float4 z = {0.f, 0.f, 0.f, 0.f};
    *(float4*)(p + idx) = z;
}

// ---------------- context[b,h] += sum_{s in chunk} attn[b,s]*enc[s,b,h] ----------------
__global__ void k_context(const float* __restrict__ attn, const float* __restrict__ enc,
                          float* __restrict__ ctx) {
    int b = blockIdx.x;
    int chunk = blockIdx.y;          // 32 chunks of 64 s
    int tid = threadIdx.x;           // h = tid*4 .. +3
    float4 acc = {0.f, 0.f, 0.f, 0.f};
    int s0 = chunk * 64;
    for (int s = s0; s < s0 + 64; ++s) {
        float w  = attn[(size_t)b * S_LEN + s];
        float4 e = *(const float4*)(enc + ((size_t)s * B_SZ + b) * H_SZ + tid * 4);
        acc.x += w * e.x; acc.y += w * e.y; acc.z += w * e.z; acc.w += w * e.w;
    }
    float* dst = ctx + (size_t)b * H_SZ + tid * 4;
    atomicAdd(dst + 0, acc.x);
    atomicAdd(dst + 1, acc.y);
    atomicAdd(dst + 2, acc.z);
    atomicAdd(dst + 3, acc.w);
}

// ---------------- C[b,j] (partial over K-split) = sum_k A[b,k] W[j,k] ----------------
// A = [A0 | A1] (k<1024 -> A0, else A1), both 64x1024 row-major. W is (3072 x K) row-major.
// 64x64 output tile per block, BK=16, 4x4 per-thread microtile.
#define BK 16
#define LDP 68   // padded LDS leading dim (4-float aligned, conflict-light)
__global__ __launch_bounds__(256) void k_gemm64(
    const float* __restrict__ A0, const float* __restrict__ A1,
    const float* __restrict__ W, float* __restrict__ Cpart,
    int K, int KS) {
    __shared__ float As[BK * LDP];
    __shared__ float Ws[BK * LDP];
    int jt = blockIdx.x;             // 48 j-tiles of 64
    int ks = blockIdx.y;             // K split
    int tid = threadIdx.x;
    int klen = K / KS;
    int kbeg = ks * klen, kend = kbeg + klen;
    int lb = tid >> 2;               // 0..63 load row
    int kq = tid & 3;                // k quad
    int ty = tid >> 4;               // 0..15 (b groups of 4)
    int tx = tid & 15;               // 0..15 (j groups of 4)
    float acc[4][4] = {};
    for (int k0 = kbeg; k0 < kend; k0 += BK) {
        int k = k0 + kq * 4;
        const float* asrc = (k < 1024) ? (A0 + (size_t)lb * 1024 + k)
                                       : (A1 + (size_t)lb * 1024 + (k - 1024));
        float4 a = *(const float4*)asrc;
        As[(kq * 4 + 0) * LDP + lb] = a.x;
        As[(kq * 4 + 1) * LDP + lb] = a.y;
        As[(kq * 4 + 2) * LDP + lb] = a.z;
        As[(kq * 4 + 3) * LDP + lb] = a.w;
        float4 wv = *(const float4*)(W + (size_t)(jt * 64 + lb) * K + k);
        Ws[(kq * 4 + 0) * LDP + lb] = wv.x;
        Ws[(kq * 4 + 1) * LDP + lb] = wv.y;
        Ws[(kq * 4 + 2) * LDP + lb] = wv.z;
        Ws[(kq * 4 + 3) * LDP + lb] = wv.w;
        __syncthreads();
#pragma unroll
        for (int kk = 0; kk < BK; ++kk) {
            float4 a4 = *(const float4*)&As[kk * LDP + ty * 4];
            float4 w4 = *(const float4*)&Ws[kk * LDP + tx * 4];
            acc[0][0] += a4.x * w4.x; acc[0][1] += a4.x * w4.y; acc[0][2] += a4.x * w4.z; acc[0][3] += a4.x * w4.w;
            acc[1][0] += a4.y * w4.x; acc[1][1] += a4.y * w4.y; acc[1][2] += a4.y * w4.z; acc[1][3] += a4.y * w4.w;
            acc[2][0] += a4.z * w4.x; acc[2][1] += a4.z * w4.y; acc[2][2] += a4.z * w4.z; acc[2][3] += a4.z * w4.w;
            acc[3][0] += a4.w * w4.x; acc[3][1] += a4.w * w4.y; acc[3][2] += a4.w * w4.z; acc[3][3] += a4.w * w4.w;
        }
        __syncthreads();
    }
#pragma unroll
    for (int i = 0; i < 4; ++i) {
        float4 o = {acc[i][0], acc[i][1], acc[i][2], acc[i][3]};
        *(float4*)(Cpart + ((size_t)(ks * 64 + ty * 4 + i)) * 3072 + jt * 64 + tx * 4) = o;
    }
}

// ---------------- GRU gates + output write ----------------
__global__ void k_gates(const float* __restrict__ gip, const float* __restrict__ ghp,
                        const float* __restrict__ b_ih, const float* __restrict__ b_hh,
                        const float* __restrict__ h, float* __restrict__ out) {
    int idx = blockIdx.x * 256 + threadIdx.x;   // 65536 = 64*1024
    int b = idx >> 10, j = idx & 1023;
    float ir = 0.f, iz = 0.f, in_ = 0.f, hr = 0.f, hz = 0.f, hn = 0.f;
#pragma unroll
    for (int ks = 0; ks < 4; ++ks) {
        const float* gi = gip + (size_t)(ks * 64 + b) * 3072;
        ir  += gi[j]; iz += gi[1024 + j]; in_ += gi[2048 + j];
        const float* gh = ghp + (size_t)(ks * 64 + b) * 3072;
        hr  += gh[j]; hz += gh[1024 + j]; hn += gh[2048 + j];
    }
    ir += b_ih[j]; iz += b_ih[1024 + j]; in_ += b_ih[2048 + j];
    hr += b_hh[j]; hz += b_hh[1024 + j]; hn += b_hh[2048 + j];
    float r = 1.f / (1.f + expf(-(ir + hr)));
    float z = 1.f / (1.f + expf(-(iz + hz)));
    float n = tanhf(in_ + r * hn);
    float hprev = h[idx];
    float hnew = (1.f - z) * n + z * hprev;
    out[idx] = hnew;            // output (B,H)
    out[65536 + idx] = hnew;    // hidden (1,B,H)
}

extern "C" void kernel_launch(void* const* d_in, const int* in_sizes, int n_in,
                              void* d_out, int out_size, void* d_ws, size_t ws_size,
                              hipStream_t stream) {
    const float* x    = (const float*)d_in[0];   // (1,64,1024)
    const float* h    = (const float*)d_in[1];   // (1,64,1024)  == h
    const float* enc  = (const float*)d_in[2];   // (2048,64,1024)
    const float* W_ih = (const float*)d_in[3];   // (3072,2048)
    const float* W_hh = (const float*)d_in[4];   // (3072,1024)
    const float* b_ih = (const float*)d_in[5];
    const float* b_hh = (const float*)d_in[6];
    float* out = (float*)d_out;                  // [output 65536 | hidden 65536 | attn 131072]
    float* ws  = (float*)d_ws;

    float* scores = ws;                        // 131072 floats
    float* ctx    = ws + 131072;               // 65536
    float* gip    = ws + 131072 + 65536;       // 4*64*3072 = 786432
    float* ghp    = gip + 786432;              // 786432
    float* attn   = out + 131072;              // attn_weights region of d_out

    k_scores <<<32768, 256, 0, stream>>>(h, enc, scores);
    k_softmax<<<64,    256, 0, stream>>>(scores, attn);
    k_zero   <<<64,    256, 0, stream>>>(ctx);
    k_context<<<dim3(64, 32), 256, 0, stream>>>(attn, enc, ctx);
    k_gemm64 <<<dim3(48, 4),  256, 0, stream>>>(x, ctx, W_ih, gip, 2048, 4);
    k_gemm64 <<<dim3(48, 4),  256, 0, stream>>>(h, h,    W_hh, ghp, 1024, 4);
    k_gates  <<<256,   256, 0, stream>>>(gip, ghp, b_ih, b_hh, h, out);
}

// Round 2
// 776.226 us; speedup vs baseline: 1.1248x; 1.1248x over previous
//
#include <hip/hip_runtime.h>
#include <math.h>

#define S_LEN 2048
#define B_SZ  64
#define H_SZ  1024
// DIN == 1024, rnn_input K = 2048

// ---------------- fused scores+softmax+context (flash-style, one enc pass) ----
// grid (64 b, 16 chunks), 256 threads = 4 waves; each wave owns 32 s-rows.
// Wave keeps h row (16 f/lane), online (m,l), ctx accumulator (16 f/lane).
__global__ __launch_bounds__(256) void k_attn(
    const float* __restrict__ h, const float* __restrict__ enc,
    float* __restrict__ scores, float* __restrict__ m_ws, float* __restrict__ l_ws,
    float* __restrict__ part) {
    int b     = blockIdx.x;            // 64
    int chunk = blockIdx.y;            // 16 chunks of 128 s
    int widx  = threadIdx.x >> 6;      // wave in block: 32 s each
    int lane  = threadIdx.x & 63;
    const float* hrow = h + (size_t)b * H_SZ;
    float4 h4[4];
#pragma unroll
    for (int i = 0; i < 4; ++i) h4[i] = *(const float4*)(hrow + i * 256 + lane * 4);
    float4 cacc[4] = {};
    float m = -1e30f, l = 0.f;
    int s0 = chunk * 128 + widx * 32;
    for (int s = s0; s < s0 + 32; ++s) {
        const float* erow = enc + ((size_t)s * B_SZ + b) * H_SZ;
        float4 e[4];
#pragma unroll
        for (int i = 0; i < 4; ++i) e[i] = *(const float4*)(erow + i * 256 + lane * 4);
        float d = 0.f;
#pragma unroll
        for (int i = 0; i < 4; ++i)
            d += e[i].x * h4[i].x + e[i].y * h4[i].y + e[i].z * h4[i].z + e[i].w * h4[i].w;
#pragma unroll
        for (int off = 32; off > 0; off >>= 1) d += __shfl_xor(d, off);
        if (lane == (s & 63)) scores[(size_t)b * S_LEN + s] = d;  // spread writers
        float nm    = fmaxf(m, d);
        float alpha = __expf(m - nm);
        float p     = __expf(d - nm);
        l = l * alpha + p;
#pragma unroll
        for (int i = 0; i < 4; ++i) {
            cacc[i].x = cacc[i].x * alpha + p * e[i].x;
            cacc[i].y = cacc[i].y * alpha + p * e[i].y;
            cacc[i].z = cacc[i].z * alpha + p * e[i].z;
            cacc[i].w = cacc[i].w * alpha + p * e[i].w;
        }
        m = nm;
    }
    int wg = ((b * 16 + chunk) << 2) + widx;      // = b*64 + (chunk*4+widx)
    if (lane == 0) { m_ws[wg] = m; l_ws[wg] = l; }
    float* pd = part + (size_t)wg * H_SZ;
#pragma unroll
    for (int i = 0; i < 4; ++i) *(float4*)(pd + i * 256 + lane * 4) = cacc[i];
}

// ---------------- combine partials: ctx + attn normalize ----------------
__global__ void k_combine(const float* __restrict__ m_ws, const float* __restrict__ l_ws,
                          const float* __restrict__ part, const float* __restrict__ scores,
                          float* __restrict__ ctx, float* __restrict__ attn) {
    int b = blockIdx.x, tid = threadIdx.x;
    float M = -1e30f;
    for (int j = 0; j < 64; ++j) M = fmaxf(M, m_ws[b * 64 + j]);
    float L = 0.f;
    for (int j = 0; j < 64; ++j) L += l_ws[b * 64 + j] * __expf(m_ws[b * 64 + j] - M);
    float invL = 1.f / L;
    float4 c = {0.f, 0.f, 0.f, 0.f};
    for (int j = 0; j < 64; ++j) {
        float coef = __expf(m_ws[b * 64 + j] - M);
        float4 p4 = *(const float4*)(part + ((size_t)(b * 64 + j)) * H_SZ + tid * 4);
        c.x += coef * p4.x; c.y += coef * p4.y; c.z += coef * p4.z; c.w += coef * p4.w;
    }
    c.x *= invL; c.y *= invL; c.z *= invL; c.w *= invL;
    *(float4*)(ctx + (size_t)b * H_SZ + tid * 4) = c;
#pragma unroll
    for (int i = 0; i < 8; ++i) {
        int s = tid + i * 256;
        attn[(size_t)b * S_LEN + s] = __expf(scores[(size_t)b * S_LEN + s] - M) * invL;
    }
}

// ---------------- C[b,j] (partial over K-split) = sum_k A[b,k] W[j,k] ----------------
// A = [A0 | A1] (k<1024 -> A0, else A1), both 64x1024 row-major. W is (3072 x K) row-major.
// 64x64 output tile per block, BK=16, 4x4 per-thread microtile.
#define BK 16
#define LDP 68   // padded LDS leading dim
#define KSPLIT 8
__global__ __launch_bounds__(256) void k_gemm64(
    const float* __restrict__ A0, const float* __restrict__ A1,
    const float* __restrict__ W, float* __restrict__ Cpart,
    int K) {
    __shared__ float As[BK * LDP];
    __shared__ float Ws[BK * LDP];
    int jt = blockIdx.x;             // 48 j-tiles of 64
    int ks = blockIdx.y;             // K split
    int tid = threadIdx.x;
    int klen = K / KSPLIT;
    int kbeg = ks * klen, kend = kbeg + klen;
    int lb = tid >> 2;               // 0..63 load row
    int kq = tid & 3;                // k quad
    int ty = tid >> 4;               // 0..15 (b groups of 4)
    int tx = tid & 15;               // 0..15 (j groups of 4)
    float acc[4][4] = {};
    for (int k0 = kbeg; k0 < kend; k0 += BK) {
        int k = k0 + kq * 4;
        const float* asrc = (k < 1024) ? (A0 + (size_t)lb * 1024 + k)
                                       : (A1 + (size_t)lb * 1024 + (k - 1024));
        float4 a = *(const float4*)asrc;
        As[(kq * 4 + 0) * LDP + lb] = a.x;
        As[(kq * 4 + 1) * LDP + lb] = a.y;
        As[(kq * 4 + 2) * LDP + lb] = a.z;
        As[(kq * 4 + 3) * LDP + lb] = a.w;
        float4 wv = *(const float4*)(W + (size_t)(jt * 64 + lb) * K + k);
        Ws[(kq * 4 + 0) * LDP + lb] = wv.x;
        Ws[(kq * 4 + 1) * LDP + lb] = wv.y;
        Ws[(kq * 4 + 2) * LDP + lb] = wv.z;
        Ws[(kq * 4 + 3) * LDP + lb] = wv.w;
        __syncthreads();
#pragma unroll
        for (int kk = 0; kk < BK; ++kk) {
            float4 a4 = *(const float4*)&As[kk * LDP + ty * 4];
            float4 w4 = *(const float4*)&Ws[kk * LDP + tx * 4];
            acc[0][0] += a4.x * w4.x; acc[0][1] += a4.x * w4.y; acc[0][2] += a4.x * w4.z; acc[0][3] += a4.x * w4.w;
            acc[1][0] += a4.y * w4.x; acc[1][1] += a4.y * w4.y; acc[1][2] += a4.y * w4.z; acc[1][3] += a4.y * w4.w;
            acc[2][0] += a4.z * w4.x; acc[2][1] += a4.z * w4.y; acc[2][2] += a4.z * w4.z; acc[2][3] += a4.z * w4.w;
            acc[3][0] += a4.w * w4.x; acc[3][1] += a4.w * w4.y; acc[3][2] += a4.w * w4.z; acc[3][3] += a4.w * w4.w;
        }
        __syncthreads();
    }
#pragma unroll
    for (int i = 0; i < 4; ++i) {
        float4 o = {acc[i][0], acc[i][1], acc[i][2], acc[i][3]};
        *(float4*)(Cpart + ((size_t)(ks * 64 + ty * 4 + i)) * 3072 + jt * 64 + tx * 4) = o;
    }
}

// ---------------- GRU gates + output write ----------------
__global__ void k_gates(const float* __restrict__ gip, const float* __restrict__ ghp,
                        const float* __restrict__ b_ih, const float* __restrict__ b_hh,
                        const float* __restrict__ h, float* __restrict__ out) {
    int idx = blockIdx.x * 256 + threadIdx.x;   // 65536 = 64*1024
    int b = idx >> 10, j = idx & 1023;
    float ir = 0.f, iz = 0.f, in_ = 0.f, hr = 0.f, hz = 0.f, hn = 0.f;
#pragma unroll
    for (int ks = 0; ks < KSPLIT; ++ks) {
        const float* gi = gip + (size_t)(ks * 64 + b) * 3072;
        ir  += gi[j]; iz += gi[1024 + j]; in_ += gi[2048 + j];
        const float* gh = ghp + (size_t)(ks * 64 + b) * 3072;
        hr  += gh[j]; hz += gh[1024 + j]; hn += gh[2048 + j];
    }
    ir += b_ih[j]; iz += b_ih[1024 + j]; in_ += b_ih[2048 + j];
    hr += b_hh[j]; hz += b_hh[1024 + j]; hn += b_hh[2048 + j];
    float r = 1.f / (1.f + __expf(-(ir + hr)));
    float z = 1.f / (1.f + __expf(-(iz + hz)));
    float n = tanhf(in_ + r * hn);
    float hprev = h[idx];
    float hnew = (1.f - z) * n + z * hprev;
    out[idx] = hnew;            // output (B,H)
    out[65536 + idx] = hnew;    // hidden (1,B,H)
}

extern "C" void kernel_launch(void* const* d_in, const int* in_sizes, int n_in,
                              void* d_out, int out_size, void* d_ws, size_t ws_size,
                              hipStream_t stream) {
    const float* x    = (const float*)d_in[0];   // (1,64,1024)
    const float* h    = (const float*)d_in[1];   // (1,64,1024)
    const float* enc  = (const float*)d_in[2];   // (2048,64,1024)
    const float* W_ih = (const float*)d_in[3];   // (3072,2048)
    const float* W_hh = (const float*)d_in[4];   // (3072,1024)
    const float* b_ih = (const float*)d_in[5];
    const float* b_hh = (const float*)d_in[6];
    float* out = (float*)d_out;                  // [output 65536 | hidden 65536 | attn 131072]
    float* ws  = (float*)d_ws;

    float* scores = ws;                         // 131072
    float* ctx    = scores + 131072;            // 65536
    float* m_ws   = ctx + 65536;                // 4096
    float* l_ws   = m_ws + 4096;                // 4096
    float* part   = l_ws + 4096;                // 4096*1024
    float* gip    = part + 4096 * 1024;         // 8*64*3072
    float* ghp    = gip + 8 * 64 * 3072;        // 8*64*3072
    float* attn   = out + 131072;

    k_attn   <<<dim3(64, 16), 256, 0, stream>>>(h, enc, scores, m_ws, l_ws, part);
    k_combine<<<64, 256, 0, stream>>>(m_ws, l_ws, part, scores, ctx, attn);
    k_gemm64 <<<dim3(48, KSPLIT), 256, 0, stream>>>(x, ctx, W_ih, gip, 2048);
    k_gemm64 <<<dim3(48, KSPLIT), 256, 0, stream>>>(h, h,    W_hh, ghp, 1024);
    k_gates  <<<256, 256, 0, stream>>>(gip, ghp, b_ih, b_hh, h, out);
}